// Round 1
// baseline (188.789 us; speedup 1.0000x reference)
//
#include <hip/hip_runtime.h>
#include <math.h>

#define BATCH  2
#define SEQ    2048
#define DMODEL 256
#define DSTATE 16
#define DINNER 512
#define DTRANK 16
#define RTOT   (BATCH*SEQ)   // 4096
#define GCH    64            // scan chunks per sequence
#define LCH    32            // chunk length (GCH*LCH == SEQ)

__device__ __forceinline__ float silu_f(float v){ return v / (1.f + __expf(-v)); }

// ---------------- kernel A: transpose + RMSNorm -> h_t [DMODEL][RTOT] ----------------
__global__ __launch_bounds__(256) void k_prep(const float* __restrict__ x,
                                              const float* __restrict__ norm_w,
                                              float* __restrict__ h_t){
  int b  = blockIdx.x >> 5;           // 32 blocks per batch
  int l0 = (blockIdx.x & 31) << 6;    // 64 l per block
  int ll = threadIdx.x & 63;
  int cq = threadIdx.x >> 6;          // c-quarter 0..3
  const float* xb = x + (size_t)b * DMODEL * SEQ;
  float ss = 0.f;
  for (int it = 0; it < 64; ++it) {
    int c = cq + it * 4;
    float v = xb[(size_t)c * SEQ + l0 + ll];
    ss += v * v;
  }
  __shared__ float red[4][64];
  red[cq][ll] = ss;
  __syncthreads();
  float s = red[0][ll] + red[1][ll] + red[2][ll] + red[3][ll];
  float r = rsqrtf(s / (float)DMODEL + 1e-5f);
  for (int it = 0; it < 64; ++it) {
    int c = cq + it * 4;
    float v = xb[(size_t)c * SEQ + l0 + ll];
    h_t[(size_t)c * RTOT + b * SEQ + l0 + ll] = v * r * norm_w[c];
  }
}

// ---------------- kernel B: GEMM1 xz[m][d] = sum_k h[m][k] * Win[d][k] ----------------
// A_t is [256][4096] (transposed), Win is [1024][256], xz is [4096][1024]
__global__ __launch_bounds__(256) void k_gemm1(const float* __restrict__ A_t,
                                               const float* __restrict__ W,
                                               float* __restrict__ xz){
  int m0 = blockIdx.x * 64;
  int n0 = blockIdx.y * 64;
  int t = threadIdx.x;
  int tx = t & 15, ty = t >> 4;
  __shared__ float As[16][64];
  __shared__ float Bs[16][64];
  float acc[4][4] = {};
  for (int k0 = 0; k0 < DMODEL; k0 += 16) {
    { // stage A (already K-major: direct float4)
      int k = t >> 4, m4 = (t & 15) * 4;
      float4 v = *reinterpret_cast<const float4*>(&A_t[(size_t)(k0 + k) * RTOT + m0 + m4]);
      *reinterpret_cast<float4*>(&As[k][m4]) = v;
    }
    { // stage B transposed: Bs[k][n] = W[n0+n][k0+k]
      int n = t >> 2, kq = (t & 3) * 4;
      float4 v = *reinterpret_cast<const float4*>(&W[(size_t)(n0 + n) * DMODEL + k0 + kq]);
      Bs[kq + 0][n] = v.x; Bs[kq + 1][n] = v.y; Bs[kq + 2][n] = v.z; Bs[kq + 3][n] = v.w;
    }
    __syncthreads();
#pragma unroll
    for (int k = 0; k < 16; ++k) {
      float a[4], bb[4];
      *reinterpret_cast<float4*>(a)  = *reinterpret_cast<const float4*>(&As[k][tx * 4]);
      *reinterpret_cast<float4*>(bb) = *reinterpret_cast<const float4*>(&Bs[k][ty * 4]);
#pragma unroll
      for (int i = 0; i < 4; ++i)
#pragma unroll
        for (int j = 0; j < 4; ++j)
          acc[i][j] += a[i] * bb[j];
    }
    __syncthreads();
  }
#pragma unroll
  for (int i = 0; i < 4; ++i) {
    float4 o = make_float4(acc[i][0], acc[i][1], acc[i][2], acc[i][3]);
    *reinterpret_cast<float4*>(&xz[(size_t)(m0 + tx * 4 + i) * 1024 + n0 + ty * 4]) = o;
  }
}

// ---------------- kernel C: depthwise causal conv (taps 4) + SiLU -> xc [RTOT][512] ----------------
__global__ __launch_bounds__(256) void k_conv(const float* __restrict__ xz,
                                              const float* __restrict__ conv_w,
                                              const float* __restrict__ conv_b,
                                              float* __restrict__ xc){
  int idx = blockIdx.x * 256 + threadIdx.x;   // [0, RTOT*512)
  int d = idx & 511;
  int row = idx >> 9;
  int l = row & (SEQ - 1);
  float4 w = *reinterpret_cast<const float4*>(&conv_w[d * 4]);
  float acc = conv_b[d];
  if (l >= 3) acc += xz[(size_t)(row - 3) * 1024 + d] * w.x;
  if (l >= 2) acc += xz[(size_t)(row - 2) * 1024 + d] * w.y;
  if (l >= 1) acc += xz[(size_t)(row - 1) * 1024 + d] * w.z;
  acc += xz[(size_t)row * 1024 + d] * w.w;
  xc[idx] = silu_f(acc);
}

// ---------------- kernel D: x_proj (48 outs) + dt_proj + softplus -> BC [RTOT][32], delta [RTOT][512] ----------------
__global__ __launch_bounds__(256) void k_xproj(const float* __restrict__ xc,
                                               const float* __restrict__ xpw,   // [48][512]
                                               const float* __restrict__ dtw,   // [512][16]
                                               const float* __restrict__ dtb,   // [512]
                                               float* __restrict__ BCbuf,
                                               float* __restrict__ delta){
  __shared__ float xcs[16][516];
  __shared__ float dts[16][16];
  int t = threadIdx.x;
  int r0 = blockIdx.x * 16;
  for (int i = 0; i < 8; ++i) {
    int f4 = i * 256 + t;
    int row = f4 >> 7;
    int c4 = f4 & 127;
    float4 v = *reinterpret_cast<const float4*>(&xc[(size_t)(r0 + row) * 512 + c4 * 4]);
    *reinterpret_cast<float4*>(&xcs[row][c4 * 4]) = v;
  }
  __syncthreads();
  for (int o = t; o < 16 * 48; o += 256) {
    int row = o / 48, e = o % 48;
    const float* wrow = &xpw[e * 512];
    float s = 0.f;
    for (int k4 = 0; k4 < 128; ++k4) {
      float4 a = *reinterpret_cast<const float4*>(&xcs[row][k4 * 4]);
      float4 w = *reinterpret_cast<const float4*>(&wrow[k4 * 4]);
      s += a.x * w.x + a.y * w.y + a.z * w.z + a.w * w.w;
    }
    if (e < 16) dts[row][e] = s;
    else BCbuf[(size_t)(r0 + row) * 32 + (e - 16)] = s;
  }
  __syncthreads();
  for (int o = t; o < 16 * 512; o += 256) {
    int row = o >> 9, d = o & 511;
    float s = dtb[d];
#pragma unroll
    for (int r = 0; r < 16; ++r) s += dts[row][r] * dtw[d * 16 + r];
    float sp = (s > 15.f) ? s : log1pf(__expf(s));
    delta[(size_t)(r0 + row) * 512 + d] = sp;
  }
}

// ---------------- kernel F: scan pass 1 (per-chunk local scan + decay product) ----------------
__global__ __launch_bounds__(256) void k_scan1(const float* __restrict__ delta,
                                               const float* __restrict__ xc,
                                               const float* __restrict__ BCbuf,
                                               const float* __restrict__ A_log,
                                               float* __restrict__ Pbuf,
                                               float* __restrict__ Sbuf){
  int bid = blockIdx.x;            // b(1) g(6) dh(1)
  int b = bid >> 7;
  int g = (bid >> 1) & 63;
  int dh = bid & 1;
  int d = dh * 256 + threadIdx.x;
  float an[16], h[16], P[16];
#pragma unroll
  for (int n = 0; n < 16; ++n) { an[n] = -__expf(A_log[d * 16 + n]); h[n] = 0.f; P[n] = 1.f; }
  int base = b * SEQ + g * LCH;
  for (int s = 0; s < LCH; ++s) {
    int row = base + s;
    float dl = delta[(size_t)row * 512 + d];
    float xv = xc[(size_t)row * 512 + d];
    float dx = dl * xv;
    const float* bc = &BCbuf[(size_t)row * 32];
#pragma unroll
    for (int n = 0; n < 16; ++n) {
      float dA = __expf(dl * an[n]);
      h[n] = dA * h[n] + dx * bc[n];
      P[n] *= dA;
    }
  }
  size_t outb = ((size_t)(b * GCH + g) * 16) * 512 + d;
#pragma unroll
  for (int n = 0; n < 16; ++n) { Sbuf[outb + (size_t)n * 512] = h[n]; Pbuf[outb + (size_t)n * 512] = P[n]; }
}

// ---------------- kernel G: sequential chunk combine -> per-chunk initial states ----------------
__global__ __launch_bounds__(256) void k_comb(const float* __restrict__ Pbuf,
                                              const float* __restrict__ Sbuf,
                                              float* __restrict__ Hinit){
  int tg = blockIdx.x * 256 + threadIdx.x;   // B*16*512 = 16384
  int d = tg & 511;
  int n = (tg >> 9) & 15;
  int b = tg >> 13;
  float h = 0.f;
  for (int g = 0; g < GCH; ++g) {
    size_t idx = ((size_t)(b * GCH + g) * 16 + n) * 512 + d;
    Hinit[idx] = h;
    h = Pbuf[idx] * h + Sbuf[idx];
  }
}

// ---------------- kernel H: scan pass 2 + y + D-skip + SiLU(z) gate -> yg [RTOT][512] ----------------
__global__ __launch_bounds__(256) void k_scan2(const float* __restrict__ delta,
                                               const float* __restrict__ xc,
                                               const float* __restrict__ BCbuf,
                                               const float* __restrict__ A_log,
                                               const float* __restrict__ Hinit,
                                               const float* __restrict__ xz,
                                               const float* __restrict__ Dw,
                                               float* __restrict__ yg){
  int bid = blockIdx.x;
  int b = bid >> 7;
  int g = (bid >> 1) & 63;
  int dh = bid & 1;
  int d = dh * 256 + threadIdx.x;
  float an[16], h[16];
  size_t hb = ((size_t)(b * GCH + g) * 16) * 512 + d;
#pragma unroll
  for (int n = 0; n < 16; ++n) { an[n] = -__expf(A_log[d * 16 + n]); h[n] = Hinit[hb + (size_t)n * 512]; }
  float Dd = Dw[d];
  int base = b * SEQ + g * LCH;
  for (int s = 0; s < LCH; ++s) {
    int row = base + s;
    float dl = delta[(size_t)row * 512 + d];
    float xv = xc[(size_t)row * 512 + d];
    float dx = dl * xv;
    const float* bc = &BCbuf[(size_t)row * 32];
    float y = 0.f;
#pragma unroll
    for (int n = 0; n < 16; ++n) {
      float dA = __expf(dl * an[n]);
      h[n] = dA * h[n] + dx * bc[n];
      y += h[n] * bc[16 + n];
    }
    float zv = xz[(size_t)row * 1024 + 512 + d];
    yg[(size_t)row * 512 + d] = (y + xv * Dd) * silu_f(zv);
  }
}

// ---------------- kernel I: GEMM3 out[b][c][l] = residual + sum_d yg[m][d]*Wout[c][d] ----------------
__global__ __launch_bounds__(256) void k_gemm3(const float* __restrict__ yg,   // [4096][512]
                                               const float* __restrict__ W,    // [256][512]
                                               const float* __restrict__ x,
                                               float* __restrict__ out){
  int m0 = blockIdx.x * 64;
  int n0 = blockIdx.y * 64;
  int t = threadIdx.x;
  int tx = t & 15, ty = t >> 4;
  __shared__ float As[16][64];
  __shared__ float Bs[16][64];
  float acc[4][4] = {};
  for (int k0 = 0; k0 < DINNER; k0 += 16) {
    { // stage A transposed: As[k][m] = yg[m0+m][k0+k]
      int m = t >> 2, kq = (t & 3) * 4;
      float4 v = *reinterpret_cast<const float4*>(&yg[(size_t)(m0 + m) * 512 + k0 + kq]);
      As[kq + 0][m] = v.x; As[kq + 1][m] = v.y; As[kq + 2][m] = v.z; As[kq + 3][m] = v.w;
    }
    {
      int n = t >> 2, kq = (t & 3) * 4;
      float4 v = *reinterpret_cast<const float4*>(&W[(size_t)(n0 + n) * 512 + k0 + kq]);
      Bs[kq + 0][n] = v.x; Bs[kq + 1][n] = v.y; Bs[kq + 2][n] = v.z; Bs[kq + 3][n] = v.w;
    }
    __syncthreads();
#pragma unroll
    for (int k = 0; k < 16; ++k) {
      float a[4], bb[4];
      *reinterpret_cast<float4*>(a)  = *reinterpret_cast<const float4*>(&As[k][tx * 4]);
      *reinterpret_cast<float4*>(bb) = *reinterpret_cast<const float4*>(&Bs[k][ty * 4]);
#pragma unroll
      for (int i = 0; i < 4; ++i)
#pragma unroll
        for (int j = 0; j < 4; ++j)
          acc[i][j] += a[i] * bb[j];
    }
    __syncthreads();
  }
  int b = m0 >> 11;
  int lb = (m0 & (SEQ - 1)) + tx * 4;
#pragma unroll
  for (int j = 0; j < 4; ++j) {
    int c = n0 + ty * 4 + j;
    size_t addr = ((size_t)(b * DMODEL + c)) * SEQ + lb;
    float4 res = *reinterpret_cast<const float4*>(&x[addr]);
    float4 o = make_float4(acc[0][j] + res.x, acc[1][j] + res.y, acc[2][j] + res.z, acc[3][j] + res.w);
    *reinterpret_cast<float4*>(&out[addr]) = o;
  }
}

extern "C" void kernel_launch(void* const* d_in, const int* in_sizes, int n_in,
                              void* d_out, int out_size, void* d_ws, size_t ws_size,
                              hipStream_t stream) {
  const float* x          = (const float*)d_in[0];
  const float* norm_w     = (const float*)d_in[1];
  const float* in_proj_w  = (const float*)d_in[2];
  const float* conv_w     = (const float*)d_in[3];
  const float* conv_b     = (const float*)d_in[4];
  const float* x_proj_w   = (const float*)d_in[5];
  const float* dt_proj_w  = (const float*)d_in[6];
  const float* dt_proj_b  = (const float*)d_in[7];
  const float* A_log      = (const float*)d_in[8];
  const float* Dw         = (const float*)d_in[9];
  const float* out_proj_w = (const float*)d_in[10];
  float* out = (float*)d_out;

  float* ws    = (float*)d_ws;
  float* h_t   = ws;                        // 256*4096
  float* xz    = h_t   + (size_t)256 * 4096;     // 4096*1024
  float* xc    = xz    + (size_t)4096 * 1024;    // 4096*512
  float* BCbuf = xc    + (size_t)4096 * 512;     // 4096*32
  float* delta = BCbuf + (size_t)4096 * 32;      // 4096*512
  float* Pbuf  = delta + (size_t)4096 * 512;     // 2*64*16*512
  float* Sbuf  = Pbuf  + (size_t)2 * 64 * 16 * 512;
  float* Hinit = Sbuf  + (size_t)2 * 64 * 16 * 512;
  float* yg    = Hinit + (size_t)2 * 64 * 16 * 512;  // 4096*512

  k_prep <<<64,           256, 0, stream>>>(x, norm_w, h_t);
  k_gemm1<<<dim3(64, 16), 256, 0, stream>>>(h_t, in_proj_w, xz);
  k_conv <<<8192,         256, 0, stream>>>(xz, conv_w, conv_b, xc);
  k_xproj<<<256,          256, 0, stream>>>(xc, x_proj_w, dt_proj_w, dt_proj_b, BCbuf, delta);
  k_scan1<<<256,          256, 0, stream>>>(delta, xc, BCbuf, A_log, Pbuf, Sbuf);
  k_comb <<<64,           256, 0, stream>>>(Pbuf, Sbuf, Hinit);
  k_scan2<<<256,          256, 0, stream>>>(delta, xc, BCbuf, A_log, Hinit, xz, Dw, yg);
  k_gemm3<<<dim3(64, 4),  256, 0, stream>>>(yg, out_proj_w, x, out);
}

// Round 2
// 149.477 us; speedup vs baseline: 1.2630x; 1.2630x over previous
//
#include <hip/hip_runtime.h>
#include <math.h>

#define BATCH  2
#define SEQ    2048
#define DMODEL 256
#define DSTATE 16
#define DINNER 512
#define DTRANK 16
#define RTOT   (BATCH*SEQ)   // 4096
#define GCH    128           // scan chunks per sequence
#define LCH    16            // chunk length (GCH*LCH == SEQ)

__device__ __forceinline__ float silu_f(float v){ return v / (1.f + __expf(-v)); }

// ---------------- kernel A: transpose + RMSNorm -> h_t [DMODEL][RTOT] ----------------
__global__ __launch_bounds__(256) void k_prep(const float* __restrict__ x,
                                              const float* __restrict__ norm_w,
                                              float* __restrict__ h_t){
  int b  = blockIdx.x >> 5;           // 32 blocks per batch
  int l0 = (blockIdx.x & 31) << 6;    // 64 l per block
  int ll = threadIdx.x & 63;
  int cq = threadIdx.x >> 6;          // c-quarter 0..3
  const float* xb = x + (size_t)b * DMODEL * SEQ;
  float ss = 0.f;
  for (int it = 0; it < 64; ++it) {
    int c = cq + it * 4;
    float v = xb[(size_t)c * SEQ + l0 + ll];
    ss += v * v;
  }
  __shared__ float red[4][64];
  red[cq][ll] = ss;
  __syncthreads();
  float s = red[0][ll] + red[1][ll] + red[2][ll] + red[3][ll];
  float r = rsqrtf(s / (float)DMODEL + 1e-5f);
  for (int it = 0; it < 64; ++it) {
    int c = cq + it * 4;
    float v = xb[(size_t)c * SEQ + l0 + ll];
    h_t[(size_t)c * RTOT + b * SEQ + l0 + ll] = v * r * norm_w[c];
  }
}

// ---------------- kernel B: GEMM1 xz[m][d] = sum_k h[m][k] * Win[d][k] ----------------
__global__ __launch_bounds__(256) void k_gemm1(const float* __restrict__ A_t,
                                               const float* __restrict__ W,
                                               float* __restrict__ xz){
  int m0 = blockIdx.x * 64;
  int n0 = blockIdx.y * 64;
  int t = threadIdx.x;
  int tx = t & 15, ty = t >> 4;
  __shared__ float As[16][64];
  __shared__ float Bs[16][64];
  float acc[4][4] = {};
  for (int k0 = 0; k0 < DMODEL; k0 += 16) {
    {
      int k = t >> 4, m4 = (t & 15) * 4;
      float4 v = *reinterpret_cast<const float4*>(&A_t[(size_t)(k0 + k) * RTOT + m0 + m4]);
      *reinterpret_cast<float4*>(&As[k][m4]) = v;
    }
    {
      int n = t >> 2, kq = (t & 3) * 4;
      float4 v = *reinterpret_cast<const float4*>(&W[(size_t)(n0 + n) * DMODEL + k0 + kq]);
      Bs[kq + 0][n] = v.x; Bs[kq + 1][n] = v.y; Bs[kq + 2][n] = v.z; Bs[kq + 3][n] = v.w;
    }
    __syncthreads();
#pragma unroll
    for (int k = 0; k < 16; ++k) {
      float a[4], bb[4];
      *reinterpret_cast<float4*>(a)  = *reinterpret_cast<const float4*>(&As[k][tx * 4]);
      *reinterpret_cast<float4*>(bb) = *reinterpret_cast<const float4*>(&Bs[k][ty * 4]);
#pragma unroll
      for (int i = 0; i < 4; ++i)
#pragma unroll
        for (int j = 0; j < 4; ++j)
          acc[i][j] += a[i] * bb[j];
    }
    __syncthreads();
  }
#pragma unroll
  for (int i = 0; i < 4; ++i) {
    float4 o = make_float4(acc[i][0], acc[i][1], acc[i][2], acc[i][3]);
    *reinterpret_cast<float4*>(&xz[(size_t)(m0 + tx * 4 + i) * 1024 + n0 + ty * 4]) = o;
  }
}

// ---------------- kernel C: depthwise causal conv (taps 4) + SiLU -> xc [RTOT][512] ----------------
__global__ __launch_bounds__(256) void k_conv(const float* __restrict__ xz,
                                              const float* __restrict__ conv_w,
                                              const float* __restrict__ conv_b,
                                              float* __restrict__ xc){
  int idx = blockIdx.x * 256 + threadIdx.x;   // [0, RTOT*512)
  int d = idx & 511;
  int row = idx >> 9;
  int l = row & (SEQ - 1);
  float4 w = *reinterpret_cast<const float4*>(&conv_w[d * 4]);
  float acc = conv_b[d];
  if (l >= 3) acc += xz[(size_t)(row - 3) * 1024 + d] * w.x;
  if (l >= 2) acc += xz[(size_t)(row - 2) * 1024 + d] * w.y;
  if (l >= 1) acc += xz[(size_t)(row - 1) * 1024 + d] * w.z;
  acc += xz[(size_t)row * 1024 + d] * w.w;
  xc[idx] = silu_f(acc);
}

// ---------------- kernel D: x_proj (48 outs) + dt_proj + softplus ----------------
// 1024 blocks x 4 rows. Phase 1: 16-lane K-split per output (conflict-free b128 LDS reads,
// coalesced weight loads), shfl_xor reduce. Phase 2: 8 outputs/thread dt_proj + softplus.
__global__ __launch_bounds__(256) void k_xproj(const float* __restrict__ xc,
                                               const float* __restrict__ xpw,   // [48][512]
                                               const float* __restrict__ dtw,   // [512][16]
                                               const float* __restrict__ dtb,   // [512]
                                               float* __restrict__ BCbuf,
                                               float* __restrict__ delta){
  __shared__ float xcs[4][512];
  __shared__ float dts[4][16];
  int t = threadIdx.x;
  int r0 = blockIdx.x * 4;
#pragma unroll
  for (int i = 0; i < 2; ++i) {
    int f4 = i * 256 + t;          // [0,512)
    int row = f4 >> 7;
    int c4 = f4 & 127;
    float4 v = *reinterpret_cast<const float4*>(&xc[(size_t)(r0 + row) * 512 + c4 * 4]);
    *reinterpret_cast<float4*>(&xcs[row][c4 * 4]) = v;
  }
  __syncthreads();
  int l = t & 15;
  int grp = t >> 4;                // 16 groups
#pragma unroll
  for (int p = 0; p < 12; ++p) {
    int o = p * 16 + grp;          // [0,192)
    int row = o / 48, e = o % 48;
    const float4* wv = reinterpret_cast<const float4*>(&xpw[e * 512]);
    const float4* av = reinterpret_cast<const float4*>(&xcs[row][0]);
    float s = 0.f;
#pragma unroll
    for (int k = 0; k < 8; ++k) {
      float4 a = av[l + 16 * k];
      float4 w = wv[l + 16 * k];
      s += a.x * w.x + a.y * w.y + a.z * w.z + a.w * w.w;
    }
    s += __shfl_xor(s, 1); s += __shfl_xor(s, 2); s += __shfl_xor(s, 4); s += __shfl_xor(s, 8);
    if (l == 0) {
      if (e < 16) dts[row][e] = s;
      else BCbuf[(size_t)(r0 + row) * 32 + (e - 16)] = s;
    }
  }
  __syncthreads();
#pragma unroll
  for (int i = 0; i < 8; ++i) {
    int o = i * 256 + t;           // [0,2048)
    int row = o >> 9, d = o & 511;
    float s = dtb[d];
#pragma unroll
    for (int r = 0; r < 16; ++r) s += dts[row][r] * dtw[d * 16 + r];
    float sp = (s > 15.f) ? s : log1pf(__expf(s));
    delta[(size_t)(r0 + row) * 512 + d] = sp;
  }
}

// ---------------- kernel F: scan pass 1 (per-chunk local scan + decay product) ----------------
__global__ __launch_bounds__(256) void k_scan1(const float* __restrict__ delta,
                                               const float* __restrict__ xc,
                                               const float* __restrict__ BCbuf,
                                               const float* __restrict__ A_log,
                                               float* __restrict__ Pbuf,
                                               float* __restrict__ Sbuf){
  int bid = blockIdx.x;            // b(1) g(7) dh(1) : 512 blocks
  int b = bid >> 8;
  int g = (bid >> 1) & 127;
  int dh = bid & 1;
  int d = dh * 256 + threadIdx.x;
  float an[16], h[16], P[16];
#pragma unroll
  for (int n = 0; n < 16; ++n) { an[n] = -__expf(A_log[d * 16 + n]); h[n] = 0.f; P[n] = 1.f; }
  int base = b * SEQ + g * LCH;
  for (int s = 0; s < LCH; ++s) {
    int row = base + s;
    float dl = delta[(size_t)row * 512 + d];
    float xv = xc[(size_t)row * 512 + d];
    float dx = dl * xv;
    const float* bc = &BCbuf[(size_t)row * 32];
#pragma unroll
    for (int n = 0; n < 16; ++n) {
      float dA = __expf(dl * an[n]);
      h[n] = dA * h[n] + dx * bc[n];
      P[n] *= dA;
    }
  }
  size_t outb = ((size_t)(b * GCH + g) * 16) * 512 + d;
#pragma unroll
  for (int n = 0; n < 16; ++n) { Sbuf[outb + (size_t)n * 512] = h[n]; Pbuf[outb + (size_t)n * 512] = P[n]; }
}

// ---------------- kernel G: sequential chunk combine (Hinit may alias Pbuf) ----------------
__global__ __launch_bounds__(256) void k_comb(float* Pbuf,
                                              const float* Sbuf,
                                              float* Hinit){
  int tg = blockIdx.x * 256 + threadIdx.x;   // B*16*512 = 16384
  int d = tg & 511;
  int n = (tg >> 9) & 15;
  int b = tg >> 13;
  float h = 0.f;
  for (int g = 0; g < GCH; ++g) {
    size_t idx = ((size_t)((b * GCH + g) * 16 + n)) * 512 + d;
    float P = Pbuf[idx];
    float S = Sbuf[idx];
    Hinit[idx] = h;
    h = P * h + S;
  }
}

// ---------------- kernel H: scan pass 2 + y + D-skip + SiLU(z) gate -> yg [RTOT][512] ----------------
__global__ __launch_bounds__(256) void k_scan2(const float* __restrict__ delta,
                                               const float* __restrict__ xc,
                                               const float* __restrict__ BCbuf,
                                               const float* __restrict__ A_log,
                                               const float* __restrict__ Hinit,
                                               const float* __restrict__ xz,
                                               const float* __restrict__ Dw,
                                               float* __restrict__ yg){
  int bid = blockIdx.x;
  int b = bid >> 8;
  int g = (bid >> 1) & 127;
  int dh = bid & 1;
  int d = dh * 256 + threadIdx.x;
  float an[16], h[16];
  size_t hb = ((size_t)(b * GCH + g) * 16) * 512 + d;
#pragma unroll
  for (int n = 0; n < 16; ++n) { an[n] = -__expf(A_log[d * 16 + n]); h[n] = Hinit[hb + (size_t)n * 512]; }
  float Dd = Dw[d];
  int base = b * SEQ + g * LCH;
  for (int s = 0; s < LCH; ++s) {
    int row = base + s;
    float dl = delta[(size_t)row * 512 + d];
    float xv = xc[(size_t)row * 512 + d];
    float dx = dl * xv;
    const float* bc = &BCbuf[(size_t)row * 32];
    float y = 0.f;
#pragma unroll
    for (int n = 0; n < 16; ++n) {
      float dA = __expf(dl * an[n]);
      h[n] = dA * h[n] + dx * bc[n];
      y += h[n] * bc[16 + n];
    }
    float zv = xz[(size_t)row * 1024 + 512 + d];
    yg[(size_t)row * 512 + d] = (y + xv * Dd) * silu_f(zv);
  }
}

// ---------------- kernel I: GEMM3 out[b][c][l] = residual + sum_d yg[m][d]*Wout[c][d] ----------------
__global__ __launch_bounds__(256) void k_gemm3(const float* __restrict__ yg,   // [4096][512]
                                               const float* __restrict__ W,    // [256][512]
                                               const float* __restrict__ x,
                                               float* __restrict__ out){
  int m0 = blockIdx.x * 64;
  int n0 = blockIdx.y * 64;
  int t = threadIdx.x;
  int tx = t & 15, ty = t >> 4;
  __shared__ float As[16][64];
  __shared__ float Bs[16][64];
  float acc[4][4] = {};
  for (int k0 = 0; k0 < DINNER; k0 += 16) {
    {
      int m = t >> 2, kq = (t & 3) * 4;
      float4 v = *reinterpret_cast<const float4*>(&yg[(size_t)(m0 + m) * 512 + k0 + kq]);
      As[kq + 0][m] = v.x; As[kq + 1][m] = v.y; As[kq + 2][m] = v.z; As[kq + 3][m] = v.w;
    }
    {
      int n = t >> 2, kq = (t & 3) * 4;
      float4 v = *reinterpret_cast<const float4*>(&W[(size_t)(n0 + n) * 512 + k0 + kq]);
      Bs[kq + 0][n] = v.x; Bs[kq + 1][n] = v.y; Bs[kq + 2][n] = v.z; Bs[kq + 3][n] = v.w;
    }
    __syncthreads();
#pragma unroll
    for (int k = 0; k < 16; ++k) {
      float a[4], bb[4];
      *reinterpret_cast<float4*>(a)  = *reinterpret_cast<const float4*>(&As[k][tx * 4]);
      *reinterpret_cast<float4*>(bb) = *reinterpret_cast<const float4*>(&Bs[k][ty * 4]);
#pragma unroll
      for (int i = 0; i < 4; ++i)
#pragma unroll
        for (int j = 0; j < 4; ++j)
          acc[i][j] += a[i] * bb[j];
    }
    __syncthreads();
  }
  int b = m0 >> 11;
  int lb = (m0 & (SEQ - 1)) + tx * 4;
#pragma unroll
  for (int j = 0; j < 4; ++j) {
    int c = n0 + ty * 4 + j;
    size_t addr = ((size_t)(b * DMODEL + c)) * SEQ + lb;
    float4 res = *reinterpret_cast<const float4*>(&x[addr]);
    float4 o = make_float4(acc[0][j] + res.x, acc[1][j] + res.y, acc[2][j] + res.z, acc[3][j] + res.w);
    *reinterpret_cast<float4*>(&out[addr]) = o;
  }
}

extern "C" void kernel_launch(void* const* d_in, const int* in_sizes, int n_in,
                              void* d_out, int out_size, void* d_ws, size_t ws_size,
                              hipStream_t stream) {
  const float* x          = (const float*)d_in[0];
  const float* norm_w     = (const float*)d_in[1];
  const float* in_proj_w  = (const float*)d_in[2];
  const float* conv_w     = (const float*)d_in[3];
  const float* conv_b     = (const float*)d_in[4];
  const float* x_proj_w   = (const float*)d_in[5];
  const float* dt_proj_w  = (const float*)d_in[6];
  const float* dt_proj_b  = (const float*)d_in[7];
  const float* A_log      = (const float*)d_in[8];
  const float* Dw         = (const float*)d_in[9];
  const float* out_proj_w = (const float*)d_in[10];
  float* out = (float*)d_out;

  float* ws    = (float*)d_ws;
  float* h_t   = ws;                                  // 256*4096        = 1M
  float* xz    = h_t   + (size_t)256 * 4096;          // 4096*1024       = 4M
  float* xc    = xz    + (size_t)4096 * 1024;         // 4096*512        = 2M
  float* BCbuf = xc    + (size_t)4096 * 512;          // 4096*32
  float* delta = BCbuf + (size_t)4096 * 32;           // 4096*512        = 2M
  float* Pbuf  = delta + (size_t)4096 * 512;          // 2*128*16*512    = 2M
  float* Sbuf  = Pbuf  + (size_t)2 * GCH * 16 * 512;  // 2*128*16*512    = 2M
  float* yg    = Sbuf  + (size_t)2 * GCH * 16 * 512;  // 4096*512        = 2M
  float* Hinit = Pbuf;  // alias: k_comb reads P before writing Hinit at same index

  k_prep <<<64,           256, 0, stream>>>(x, norm_w, h_t);
  k_gemm1<<<dim3(64, 16), 256, 0, stream>>>(h_t, in_proj_w, xz);
  k_conv <<<8192,         256, 0, stream>>>(xz, conv_w, conv_b, xc);
  k_xproj<<<1024,         256, 0, stream>>>(xc, x_proj_w, dt_proj_w, dt_proj_b, BCbuf, delta);
  k_scan1<<<512,          256, 0, stream>>>(delta, xc, BCbuf, A_log, Pbuf, Sbuf);
  k_comb <<<64,           256, 0, stream>>>(Pbuf, Sbuf, Hinit);
  k_scan2<<<512,          256, 0, stream>>>(delta, xc, BCbuf, A_log, Hinit, xz, Dw, yg);
  k_gemm3<<<dim3(64, 4),  256, 0, stream>>>(yg, out_proj_w, x, out);
}

// Round 3
// 117.810 us; speedup vs baseline: 1.6025x; 1.2688x over previous
//
#include <hip/hip_runtime.h>
#include <hip/hip_bf16.h>
#include <math.h>

#define BATCH  2
#define SEQ    2048
#define DMODEL 256
#define DSTATE 16
#define DINNER 512
#define DTRANK 16
#define RTOT   (BATCH*SEQ)   // 4096
#define GCH    128           // scan chunks per sequence
#define LCH    16            // chunk length (GCH*LCH == SEQ)

typedef float f32x4 __attribute__((ext_vector_type(4)));
typedef short s16x8 __attribute__((ext_vector_type(8)));

__device__ __forceinline__ float silu_f(float v){ return v / (1.f + __expf(-v)); }
__device__ __forceinline__ ushort f2bf(float f){
  __hip_bfloat16 h = __float2bfloat16(f);
  return *reinterpret_cast<ushort*>(&h);
}

// ---------------- kernel 0: convert weights fp32 -> bf16 ----------------
#define NW1 (2*DINNER*DMODEL)   // in_proj 1024*256 = 262144
#define NW2 (DMODEL*DINNER)     // out_proj 256*512 = 131072
__global__ __launch_bounds__(256) void k_cvt(const float* __restrict__ w1,
                                             const float* __restrict__ w2,
                                             ushort* __restrict__ o1,
                                             ushort* __restrict__ o2){
  int i = blockIdx.x * 256 + threadIdx.x;
  if (i < NW1) o1[i] = f2bf(w1[i]);
  else { int j = i - NW1; if (j < NW2) o2[j] = f2bf(w2[j]); }
}

// ---------------- kernel A: transpose + RMSNorm -> hb bf16 [RTOT][DMODEL] ----------------
__global__ __launch_bounds__(256) void k_prep(const float* __restrict__ x,
                                              const float* __restrict__ norm_w,
                                              ushort* __restrict__ hb){
  __shared__ ushort Ls[64][272];   // 64 l-rows x 256 c (pad 272 shorts = 544B rows)
  __shared__ float red[4][64];
  int b  = blockIdx.x >> 5;
  int l0 = (blockIdx.x & 31) << 6;
  int t  = threadIdx.x;
  int ll = t & 63, cq = t >> 6;
  const float* xb = x + (size_t)b * DMODEL * SEQ;
  float ss = 0.f;
  for (int it = 0; it < 64; ++it) {
    int c = cq * 64 + it;
    float v = xb[(size_t)c * SEQ + l0 + ll];
    ss += v * v;
  }
  red[cq][ll] = ss;
  __syncthreads();
  float s = red[0][ll] + red[1][ll] + red[2][ll] + red[3][ll];
  float r = rsqrtf(s / (float)DMODEL + 1e-5f);
  for (int it = 0; it < 64; ++it) {
    int c = cq * 64 + it;
    float v = xb[(size_t)c * SEQ + l0 + ll];
    Ls[ll][c] = f2bf(v * r * norm_w[c]);
  }
  __syncthreads();
  int row = t >> 2;                 // 0..63
#pragma unroll
  for (int i = 0; i < 8; ++i) {
    int ch = (t & 3) + i * 4;       // 0..31 (16B chunks)
    int4 v = *reinterpret_cast<const int4*>(&Ls[row][ch * 8]);
    *reinterpret_cast<int4*>(&hb[((size_t)(b * SEQ + l0 + row)) * DMODEL + ch * 8]) = v;
  }
}

// ---------------- kernel B: GEMM1 (bf16 MFMA) xz[m][n] = sum_k hb[m][k]*Win[n][k] ----------------
__global__ __launch_bounds__(256) void k_gemm1(const ushort* __restrict__ A,   // [4096][256] bf16
                                               const ushort* __restrict__ B,   // [1024][256] bf16
                                               float* __restrict__ xz){
  __shared__ ushort Als[128][72];
  __shared__ ushort Bls[128][72];
  int m0 = blockIdx.x * 128, n0 = blockIdx.y * 128;
  int t = threadIdx.x;
  int w = t >> 6, l = t & 63;
  int wr = w >> 1, wc = w & 1;
  f32x4 acc[4][4] = {};
  int sr = t >> 3, sc = t & 7;
  for (int k0 = 0; k0 < DMODEL; k0 += 64) {
#pragma unroll
    for (int p = 0; p < 4; ++p) {
      int r = sr + p * 32;
      *reinterpret_cast<int4*>(&Als[r][sc * 8]) =
        *reinterpret_cast<const int4*>(&A[((size_t)(m0 + r)) * DMODEL + k0 + sc * 8]);
      *reinterpret_cast<int4*>(&Bls[r][sc * 8]) =
        *reinterpret_cast<const int4*>(&B[((size_t)(n0 + r)) * DMODEL + k0 + sc * 8]);
    }
    __syncthreads();
#pragma unroll
    for (int ks = 0; ks < 2; ++ks) {
      s16x8 af[4], bf[4];
      int kk = ks * 32 + 8 * (l >> 4);
#pragma unroll
      for (int i = 0; i < 4; ++i) {
        af[i] = *reinterpret_cast<const s16x8*>(&Als[wr * 64 + i * 16 + (l & 15)][kk]);
        bf[i] = *reinterpret_cast<const s16x8*>(&Bls[wc * 64 + i * 16 + (l & 15)][kk]);
      }
#pragma unroll
      for (int mi = 0; mi < 4; ++mi)
#pragma unroll
        for (int ni = 0; ni < 4; ++ni)
          acc[mi][ni] = __builtin_amdgcn_mfma_f32_16x16x32_bf16(af[mi], bf[ni], acc[mi][ni], 0, 0, 0);
    }
    __syncthreads();
  }
  int rq = l >> 4, cc = l & 15;
#pragma unroll
  for (int mi = 0; mi < 4; ++mi)
#pragma unroll
    for (int ni = 0; ni < 4; ++ni) {
      int n = n0 + wc * 64 + ni * 16 + cc;
      int mB = m0 + wr * 64 + mi * 16 + rq * 4;
#pragma unroll
      for (int r2 = 0; r2 < 4; ++r2)
        xz[(size_t)(mB + r2) * 1024 + n] = acc[mi][ni][r2];
    }
}

// ---------------- kernel C: depthwise causal conv (taps 4) + SiLU -> xc [RTOT][512] ----------------
__global__ __launch_bounds__(256) void k_conv(const float* __restrict__ xz,
                                              const float* __restrict__ conv_w,
                                              const float* __restrict__ conv_b,
                                              float* __restrict__ xc){
  int idx = blockIdx.x * 256 + threadIdx.x;   // [0, RTOT*512)
  int d = idx & 511;
  int row = idx >> 9;
  int l = row & (SEQ - 1);
  float4 w = *reinterpret_cast<const float4*>(&conv_w[d * 4]);
  float acc = conv_b[d];
  if (l >= 3) acc += xz[(size_t)(row - 3) * 1024 + d] * w.x;
  if (l >= 2) acc += xz[(size_t)(row - 2) * 1024 + d] * w.y;
  if (l >= 1) acc += xz[(size_t)(row - 1) * 1024 + d] * w.z;
  acc += xz[(size_t)row * 1024 + d] * w.w;
  xc[idx] = silu_f(acc);
}

// ---------------- kernel D: x_proj (48 outs) + dt_proj + softplus ----------------
__global__ __launch_bounds__(256) void k_xproj(const float* __restrict__ xc,
                                               const float* __restrict__ xpw,   // [48][512]
                                               const float* __restrict__ dtw,   // [512][16]
                                               const float* __restrict__ dtb,   // [512]
                                               float* __restrict__ BCbuf,
                                               float* __restrict__ delta){
  __shared__ float xcs[4][512];
  __shared__ float dts[4][16];
  int t = threadIdx.x;
  int r0 = blockIdx.x * 4;
#pragma unroll
  for (int i = 0; i < 2; ++i) {
    int f4 = i * 256 + t;
    int row = f4 >> 7;
    int c4 = f4 & 127;
    float4 v = *reinterpret_cast<const float4*>(&xc[(size_t)(r0 + row) * 512 + c4 * 4]);
    *reinterpret_cast<float4*>(&xcs[row][c4 * 4]) = v;
  }
  __syncthreads();
  int l = t & 15;
  int grp = t >> 4;
#pragma unroll
  for (int p = 0; p < 12; ++p) {
    int o = p * 16 + grp;
    int row = o / 48, e = o % 48;
    const float4* wv = reinterpret_cast<const float4*>(&xpw[e * 512]);
    const float4* av = reinterpret_cast<const float4*>(&xcs[row][0]);
    float s = 0.f;
#pragma unroll
    for (int k = 0; k < 8; ++k) {
      float4 a = av[l + 16 * k];
      float4 w = wv[l + 16 * k];
      s += a.x * w.x + a.y * w.y + a.z * w.z + a.w * w.w;
    }
    s += __shfl_xor(s, 1); s += __shfl_xor(s, 2); s += __shfl_xor(s, 4); s += __shfl_xor(s, 8);
    if (l == 0) {
      if (e < 16) dts[row][e] = s;
      else BCbuf[(size_t)(r0 + row) * 32 + (e - 16)] = s;
    }
  }
  __syncthreads();
#pragma unroll
  for (int i = 0; i < 8; ++i) {
    int o = i * 256 + t;
    int row = o >> 9, d = o & 511;
    float s = dtb[d];
#pragma unroll
    for (int r = 0; r < 16; ++r) s += dts[row][r] * dtw[d * 16 + r];
    float sp = (s > 15.f) ? s : log1pf(__expf(s));
    delta[(size_t)(r0 + row) * 512 + d] = sp;
  }
}

// ---------------- kernel F: scan pass 1 ----------------
__global__ __launch_bounds__(256) void k_scan1(const float* __restrict__ delta,
                                               const float* __restrict__ xc,
                                               const float* __restrict__ BCbuf,
                                               const float* __restrict__ A_log,
                                               float* __restrict__ Pbuf,
                                               float* __restrict__ Sbuf){
  int bid = blockIdx.x;            // b(1) g(7) dh(1) : 512 blocks
  int b = bid >> 8;
  int g = (bid >> 1) & 127;
  int dh = bid & 1;
  int d = dh * 256 + threadIdx.x;
  float an[16], h[16], P[16];
#pragma unroll
  for (int n = 0; n < 16; ++n) { an[n] = -__expf(A_log[d * 16 + n]); h[n] = 0.f; P[n] = 1.f; }
  int base = b * SEQ + g * LCH;
  for (int s = 0; s < LCH; ++s) {
    int row = base + s;
    float dl = delta[(size_t)row * 512 + d];
    float xv = xc[(size_t)row * 512 + d];
    float dx = dl * xv;
    const float* bc = &BCbuf[(size_t)row * 32];
#pragma unroll
    for (int n = 0; n < 16; ++n) {
      float dA = __expf(dl * an[n]);
      h[n] = dA * h[n] + dx * bc[n];
      P[n] *= dA;
    }
  }
  size_t outb = ((size_t)(b * GCH + g) * 16) * 512 + d;
#pragma unroll
  for (int n = 0; n < 16; ++n) { Sbuf[outb + (size_t)n * 512] = h[n]; Pbuf[outb + (size_t)n * 512] = P[n]; }
}

// ---------------- kernel G: sequential chunk combine (Hinit aliases Pbuf) ----------------
__global__ __launch_bounds__(256) void k_comb(float* Pbuf,
                                              const float* Sbuf,
                                              float* Hinit){
  int tg = blockIdx.x * 256 + threadIdx.x;   // B*16*512 = 16384
  int d = tg & 511;
  int n = (tg >> 9) & 15;
  int b = tg >> 13;
  float h = 0.f;
  for (int g = 0; g < GCH; ++g) {
    size_t idx = ((size_t)((b * GCH + g) * 16 + n)) * 512 + d;
    float P = Pbuf[idx];
    float S = Sbuf[idx];
    Hinit[idx] = h;
    h = P * h + S;
  }
}

// ---------------- kernel H: scan pass 2 + gate -> yg bf16 [RTOT][512] ----------------
__global__ __launch_bounds__(256) void k_scan2(const float* __restrict__ delta,
                                               const float* __restrict__ xc,
                                               const float* __restrict__ BCbuf,
                                               const float* __restrict__ A_log,
                                               const float* __restrict__ Hinit,
                                               const float* __restrict__ xz,
                                               const float* __restrict__ Dw,
                                               ushort* __restrict__ yg){
  int bid = blockIdx.x;
  int b = bid >> 8;
  int g = (bid >> 1) & 127;
  int dh = bid & 1;
  int d = dh * 256 + threadIdx.x;
  float an[16], h[16];
  size_t hb = ((size_t)(b * GCH + g) * 16) * 512 + d;
#pragma unroll
  for (int n = 0; n < 16; ++n) { an[n] = -__expf(A_log[d * 16 + n]); h[n] = Hinit[hb + (size_t)n * 512]; }
  float Dd = Dw[d];
  int base = b * SEQ + g * LCH;
  for (int s = 0; s < LCH; ++s) {
    int row = base + s;
    float dl = delta[(size_t)row * 512 + d];
    float xv = xc[(size_t)row * 512 + d];
    float dx = dl * xv;
    const float* bc = &BCbuf[(size_t)row * 32];
    float y = 0.f;
#pragma unroll
    for (int n = 0; n < 16; ++n) {
      float dA = __expf(dl * an[n]);
      h[n] = dA * h[n] + dx * bc[n];
      y += h[n] * bc[16 + n];
    }
    float zv = xz[(size_t)row * 1024 + 512 + d];
    yg[(size_t)row * 512 + d] = f2bf((y + xv * Dd) * silu_f(zv));
  }
}

// ---------------- kernel I: GEMM3 (bf16 MFMA) out[b][c][l] = residual + yg·Wout^T ----------------
__global__ __launch_bounds__(256) void k_gemm3(const ushort* __restrict__ A,   // yg [4096][512] bf16
                                               const ushort* __restrict__ B,   // wout [256][512] bf16
                                               const float* __restrict__ x,
                                               float* __restrict__ out){
  __shared__ ushort Als[128][72];
  __shared__ ushort Bls[64][72];
  int m0 = blockIdx.x * 128, n0 = blockIdx.y * 64;
  int t = threadIdx.x;
  int w = t >> 6, l = t & 63;
  int wr = w >> 1, wc = w & 1;
  f32x4 acc[4][2] = {};
  int sr = t >> 3, sc = t & 7;
  for (int k0 = 0; k0 < DINNER; k0 += 64) {
#pragma unroll
    for (int p = 0; p < 4; ++p) {
      int r = sr + p * 32;
      *reinterpret_cast<int4*>(&Als[r][sc * 8]) =
        *reinterpret_cast<const int4*>(&A[((size_t)(m0 + r)) * DINNER + k0 + sc * 8]);
    }
#pragma unroll
    for (int p = 0; p < 2; ++p) {
      int r = sr + p * 32;
      *reinterpret_cast<int4*>(&Bls[r][sc * 8]) =
        *reinterpret_cast<const int4*>(&B[((size_t)(n0 + r)) * DINNER + k0 + sc * 8]);
    }
    __syncthreads();
#pragma unroll
    for (int ks = 0; ks < 2; ++ks) {
      s16x8 af[4], bf[2];
      int kk = ks * 32 + 8 * (l >> 4);
#pragma unroll
      for (int i = 0; i < 4; ++i)
        af[i] = *reinterpret_cast<const s16x8*>(&Als[wr * 64 + i * 16 + (l & 15)][kk]);
#pragma unroll
      for (int i = 0; i < 2; ++i)
        bf[i] = *reinterpret_cast<const s16x8*>(&Bls[wc * 32 + i * 16 + (l & 15)][kk]);
#pragma unroll
      for (int mi = 0; mi < 4; ++mi)
#pragma unroll
        for (int ni = 0; ni < 2; ++ni)
          acc[mi][ni] = __builtin_amdgcn_mfma_f32_16x16x32_bf16(af[mi], bf[ni], acc[mi][ni], 0, 0, 0);
    }
    __syncthreads();
  }
  int rq = l >> 4, cc = l & 15;
#pragma unroll
  for (int mi = 0; mi < 4; ++mi)
#pragma unroll
    for (int ni = 0; ni < 2; ++ni) {
      int n = n0 + wc * 32 + ni * 16 + cc;
      int mB = m0 + wr * 64 + mi * 16 + rq * 4;
#pragma unroll
      for (int r2 = 0; r2 < 4; ++r2) {
        int m = mB + r2;
        int b = m >> 11;
        int lb = m & (SEQ - 1);
        size_t addr = ((size_t)(b * DMODEL + n)) * SEQ + lb;
        out[addr] = acc[mi][ni][r2] + x[addr];
      }
    }
}

extern "C" void kernel_launch(void* const* d_in, const int* in_sizes, int n_in,
                              void* d_out, int out_size, void* d_ws, size_t ws_size,
                              hipStream_t stream) {
  const float* x          = (const float*)d_in[0];
  const float* norm_w     = (const float*)d_in[1];
  const float* in_proj_w  = (const float*)d_in[2];
  const float* conv_w     = (const float*)d_in[3];
  const float* conv_b     = (const float*)d_in[4];
  const float* x_proj_w   = (const float*)d_in[5];
  const float* dt_proj_w  = (const float*)d_in[6];
  const float* dt_proj_b  = (const float*)d_in[7];
  const float* A_log      = (const float*)d_in[8];
  const float* Dw         = (const float*)d_in[9];
  const float* out_proj_w = (const float*)d_in[10];
  float* out = (float*)d_out;

  float* ws    = (float*)d_ws;
  float* xz    = ws;                                  // 4096*1024 f           = 16MB
  float* xc    = xz    + (size_t)4096 * 1024;         // 4096*512              = 8MB
  float* BCbuf = xc    + (size_t)4096 * 512;          // 4096*32
  float* delta = BCbuf + (size_t)4096 * 32;           // 4096*512              = 8MB
  float* Pbuf  = delta + (size_t)4096 * 512;          // 2*128*16*512          = 8MB
  float* Sbuf  = Pbuf  + (size_t)2 * GCH * 16 * 512;  // 2*128*16*512          = 8MB
  float* bfp   = Sbuf  + (size_t)2 * GCH * 16 * 512;  // bf16 region start
  ushort* hb   = (ushort*)bfp;                        // 4096*256 bf16         = 2MB
  ushort* wib  = hb  + (size_t)4096 * 256;            // 1024*256 bf16
  ushort* wob  = wib + (size_t)1024 * 256;            // 256*512 bf16
  ushort* ygb  = wob + (size_t)256 * 512;             // 4096*512 bf16         = 4MB
  float* Hinit = Pbuf;  // alias: k_comb reads P before writing Hinit at same index

  k_cvt  <<<1536,         256, 0, stream>>>(in_proj_w, out_proj_w, wib, wob);
  k_prep <<<64,           256, 0, stream>>>(x, norm_w, hb);
  k_gemm1<<<dim3(32, 8),  256, 0, stream>>>(hb, wib, xz);
  k_conv <<<8192,         256, 0, stream>>>(xz, conv_w, conv_b, xc);
  k_xproj<<<1024,         256, 0, stream>>>(xc, x_proj_w, dt_proj_w, dt_proj_b, BCbuf, delta);
  k_scan1<<<512,          256, 0, stream>>>(delta, xc, BCbuf, A_log, Pbuf, Sbuf);
  k_comb <<<64,           256, 0, stream>>>(Pbuf, Sbuf, Hinit);
  k_scan2<<<512,          256, 0, stream>>>(delta, xc, BCbuf, A_log, Hinit, xz, Dw, ygb);
  k_gemm3<<<dim3(32, 4),  256, 0, stream>>>(ygb, wob, x, out);
}

// Round 4
// 100.754 us; speedup vs baseline: 1.8738x; 1.1693x over previous
//
#include <hip/hip_runtime.h>
#include <hip/hip_bf16.h>
#include <math.h>

#define BATCH  2
#define SEQ    2048
#define DMODEL 256
#define DSTATE 16
#define DINNER 512
#define DTRANK 16
#define RTOT   (BATCH*SEQ)   // 4096
#define GCH    128           // scan chunks per sequence
#define LCH    16            // chunk length (GCH*LCH == SEQ)

typedef float f32x4 __attribute__((ext_vector_type(4)));
typedef short s16x8 __attribute__((ext_vector_type(8)));

__device__ __forceinline__ float silu_f(float v){ return v / (1.f + __expf(-v)); }
__device__ __forceinline__ ushort f2bf(float f){
  __hip_bfloat16 h = __float2bfloat16(f);
  return *reinterpret_cast<ushort*>(&h);
}
__device__ __forceinline__ float bf2f(ushort u){
  union { unsigned int i; float f; } c; c.i = ((unsigned int)u) << 16; return c.f;
}

// ---------------- kernel 1: prep (RMSNorm+transpose) + weight cvt + A-table ----------------
#define NW1 (2*DINNER*DMODEL)   // 262144
#define NW2 (DMODEL*DINNER)     // 131072
__global__ __launch_bounds__(256) void k_prep(const float* __restrict__ x,
                                              const float* __restrict__ norm_w,
                                              const float* __restrict__ w1,
                                              const float* __restrict__ w2,
                                              const float* __restrict__ A_log,
                                              ushort* __restrict__ hb,
                                              ushort* __restrict__ o1,
                                              ushort* __restrict__ o2,
                                              float* __restrict__ anv){
  int bid = blockIdx.x;
  int t = threadIdx.x;
  if (bid >= 448) {              // A-table: anv[n*512+d] = -exp(A_log[d*16+n]) ; 2 blocks
    int d = (bid - 448) * 256 + t;     // [0,512)
#pragma unroll
    for (int n = 0; n < 16; ++n)
      anv[n * 512 + d] = -__expf(A_log[d * 16 + n]);
    return;
  }
  if (bid >= 64) {               // weight cvt: 384 blocks x 1024 elems
    int base = (bid - 64) * 1024 + t * 4;
    if (base < NW1) {
      float4 v = *reinterpret_cast<const float4*>(&w1[base]);
      ushort4 o; o.x = f2bf(v.x); o.y = f2bf(v.y); o.z = f2bf(v.z); o.w = f2bf(v.w);
      *reinterpret_cast<ushort4*>(&o1[base]) = o;
    } else {
      int j = base - NW1;
      float4 v = *reinterpret_cast<const float4*>(&w2[j]);
      ushort4 o; o.x = f2bf(v.x); o.y = f2bf(v.y); o.z = f2bf(v.z); o.w = f2bf(v.w);
      *reinterpret_cast<ushort4*>(&o2[j]) = o;
    }
    return;
  }
  // prep: 64 blocks
  __shared__ ushort Ls[64][272];
  __shared__ float red[4][64];
  int b  = bid >> 5;
  int l0 = (bid & 31) << 6;
  int ll = t & 63, cq = t >> 6;
  const float* xb = x + (size_t)b * DMODEL * SEQ;
  float ss = 0.f;
  for (int it = 0; it < 64; ++it) {
    int c = cq * 64 + it;
    float v = xb[(size_t)c * SEQ + l0 + ll];
    ss += v * v;
  }
  red[cq][ll] = ss;
  __syncthreads();
  float s = red[0][ll] + red[1][ll] + red[2][ll] + red[3][ll];
  float r = rsqrtf(s / (float)DMODEL + 1e-5f);
  for (int it = 0; it < 64; ++it) {
    int c = cq * 64 + it;
    float v = xb[(size_t)c * SEQ + l0 + ll];
    Ls[ll][c] = f2bf(v * r * norm_w[c]);
  }
  __syncthreads();
  int row = t >> 2;
#pragma unroll
  for (int i = 0; i < 8; ++i) {
    int ch = (t & 3) + i * 4;
    int4 v = *reinterpret_cast<const int4*>(&Ls[row][ch * 8]);
    *reinterpret_cast<int4*>(&hb[((size_t)(b * SEQ + l0 + row)) * DMODEL + ch * 8]) = v;
  }
}

// ---------------- kernel 2: GEMM1 (bf16 MFMA) xz[m][n] (bf16 out) ----------------
__global__ __launch_bounds__(256) void k_gemm1(const ushort* __restrict__ A,   // [4096][256]
                                               const ushort* __restrict__ B,   // [1024][256]
                                               ushort* __restrict__ xzb){
  __shared__ ushort Als[128][72];
  __shared__ ushort Bls[128][72];
  int m0 = blockIdx.x * 128, n0 = blockIdx.y * 128;
  int t = threadIdx.x;
  int w = t >> 6, l = t & 63;
  int wr = w >> 1, wc = w & 1;
  f32x4 acc[4][4] = {};
  int sr = t >> 3, sc = t & 7;
  for (int k0 = 0; k0 < DMODEL; k0 += 64) {
#pragma unroll
    for (int p = 0; p < 4; ++p) {
      int r = sr + p * 32;
      *reinterpret_cast<int4*>(&Als[r][sc * 8]) =
        *reinterpret_cast<const int4*>(&A[((size_t)(m0 + r)) * DMODEL + k0 + sc * 8]);
      *reinterpret_cast<int4*>(&Bls[r][sc * 8]) =
        *reinterpret_cast<const int4*>(&B[((size_t)(n0 + r)) * DMODEL + k0 + sc * 8]);
    }
    __syncthreads();
#pragma unroll
    for (int ks = 0; ks < 2; ++ks) {
      s16x8 af[4], bf[4];
      int kk = ks * 32 + 8 * (l >> 4);
#pragma unroll
      for (int i = 0; i < 4; ++i) {
        af[i] = *reinterpret_cast<const s16x8*>(&Als[wr * 64 + i * 16 + (l & 15)][kk]);
        bf[i] = *reinterpret_cast<const s16x8*>(&Bls[wc * 64 + i * 16 + (l & 15)][kk]);
      }
#pragma unroll
      for (int mi = 0; mi < 4; ++mi)
#pragma unroll
        for (int ni = 0; ni < 4; ++ni)
          acc[mi][ni] = __builtin_amdgcn_mfma_f32_16x16x32_bf16(af[mi], bf[ni], acc[mi][ni], 0, 0, 0);
    }
    __syncthreads();
  }
  int rq = l >> 4, cc = l & 15;
#pragma unroll
  for (int mi = 0; mi < 4; ++mi)
#pragma unroll
    for (int ni = 0; ni < 4; ++ni) {
      int n = n0 + wc * 64 + ni * 16 + cc;
      int mB = m0 + wr * 64 + mi * 16 + rq * 4;
#pragma unroll
      for (int r2 = 0; r2 < 4; ++r2)
        xzb[(size_t)(mB + r2) * 1024 + n] = f2bf(acc[mi][ni][r2]);
    }
}

// ---------------- kernel 3: conv+SiLU + gate + x_proj + dt_proj (fused) ----------------
__global__ __launch_bounds__(256) void k_cxp(const ushort* __restrict__ xzb,
                                             const float* __restrict__ conv_w,
                                             const float* __restrict__ conv_b,
                                             const float* __restrict__ xpw,   // [48][512]
                                             const float* __restrict__ dtw,   // [512][16]
                                             const float* __restrict__ dtb,
                                             ushort* __restrict__ xcb,
                                             ushort* __restrict__ gb,
                                             float* __restrict__ BCbuf,
                                             ushort* __restrict__ deltab){
  __shared__ float xcs[4][520];
  __shared__ float dts[4][16];
  int t = threadIdx.x;
  int r0 = blockIdx.x * 4;
  int b = r0 >> 11;
  int l0 = r0 & (SEQ - 1);
  int rr = t >> 6;
  int dbase = (t & 63) * 8;
  int l = l0 + rr;
  size_t rowg = (size_t)b * SEQ + l;
  float acc[8];
  float4 cw[8];
#pragma unroll
  for (int dd = 0; dd < 8; ++dd) {
    cw[dd] = *reinterpret_cast<const float4*>(&conv_w[(dbase + dd) * 4]);
    acc[dd] = conv_b[dbase + dd];
  }
#pragma unroll
  for (int k = 0; k < 4; ++k) {
    int ls = l - 3 + k;
    if (ls >= 0) {
      ushort u[8];
      *reinterpret_cast<int4*>(u) =
        *reinterpret_cast<const int4*>(&xzb[((size_t)b * SEQ + ls) * 1024 + dbase]);
#pragma unroll
      for (int dd = 0; dd < 8; ++dd) {
        float wv = (k == 0) ? cw[dd].x : (k == 1) ? cw[dd].y : (k == 2) ? cw[dd].z : cw[dd].w;
        acc[dd] += bf2f(u[dd]) * wv;
      }
    }
  }
  {
    ushort uz[8], outx[8], outg[8];
    *reinterpret_cast<int4*>(uz) =
      *reinterpret_cast<const int4*>(&xzb[rowg * 1024 + 512 + dbase]);
#pragma unroll
    for (int dd = 0; dd < 8; ++dd) {
      float v = silu_f(acc[dd]);
      xcs[rr][dbase + dd] = v;
      outx[dd] = f2bf(v);
      outg[dd] = f2bf(silu_f(bf2f(uz[dd])));
    }
    *reinterpret_cast<int4*>(&xcb[rowg * 512 + dbase]) = *reinterpret_cast<int4*>(outx);
    *reinterpret_cast<int4*>(&gb [rowg * 512 + dbase]) = *reinterpret_cast<int4*>(outg);
  }
  __syncthreads();
  // x_proj: 192 outputs (4 rows x 48), 16-lane K-split + shfl reduce
  int lane = t & 15;
  int grp = t >> 4;
#pragma unroll
  for (int p = 0; p < 12; ++p) {
    int o = p * 16 + grp;
    int row = o / 48, e = o % 48;
    const float4* wv = reinterpret_cast<const float4*>(&xpw[e * 512]);
    const float4* av = reinterpret_cast<const float4*>(&xcs[row][0]);
    float s = 0.f;
#pragma unroll
    for (int k = 0; k < 8; ++k) {
      float4 a = av[lane + 16 * k];
      float4 w = wv[lane + 16 * k];
      s += a.x * w.x + a.y * w.y + a.z * w.z + a.w * w.w;
    }
    s += __shfl_xor(s, 1); s += __shfl_xor(s, 2); s += __shfl_xor(s, 4); s += __shfl_xor(s, 8);
    if (lane == 0) {
      if (e < 16) dts[row][e] = s;
      else BCbuf[(size_t)(r0 + row) * 32 + (e - 16)] = s;
    }
  }
  __syncthreads();
  // dt_proj + softplus -> delta bf16
#pragma unroll
  for (int i = 0; i < 8; ++i) {
    int o = i * 256 + t;
    int row = o >> 9, d = o & 511;
    float s = dtb[d];
#pragma unroll
    for (int r = 0; r < 16; ++r) s += dts[row][r] * dtw[d * 16 + r];
    float sp = (s > 15.f) ? s : log1pf(__expf(s));
    deltab[(size_t)(r0 + row) * 512 + d] = f2bf(sp);
  }
}

// ---------------- kernel 4: scan pass 1 ----------------
__global__ __launch_bounds__(256) void k_scan1(const ushort* __restrict__ deltab,
                                               const ushort* __restrict__ xcb,
                                               const float* __restrict__ BCbuf,
                                               const float* __restrict__ anv,
                                               float* __restrict__ Pbuf,
                                               float* __restrict__ Sbuf){
  __shared__ float bcs[LCH][32];
  int bid = blockIdx.x;            // 512 blocks
  int b = bid >> 8;
  int g = (bid >> 1) & 127;
  int dh = bid & 1;
  int d = dh * 256 + threadIdx.x;
  int base = b * SEQ + g * LCH;
  {
    float2 v = *reinterpret_cast<const float2*>(&BCbuf[(size_t)base * 32 + threadIdx.x * 2]);
    *reinterpret_cast<float2*>(&((float*)bcs)[threadIdx.x * 2]) = v;
  }
  __syncthreads();
  float an[16], h[16], P[16];
#pragma unroll
  for (int n = 0; n < 16; ++n) { an[n] = anv[n * 512 + d]; h[n] = 0.f; P[n] = 1.f; }
  for (int s = 0; s < LCH; ++s) {
    int row = base + s;
    float dl = bf2f(deltab[(size_t)row * 512 + d]);
    float xv = bf2f(xcb[(size_t)row * 512 + d]);
    float dx = dl * xv;
#pragma unroll
    for (int n = 0; n < 16; ++n) {
      float dA = __expf(dl * an[n]);
      h[n] = dA * h[n] + dx * bcs[s][n];
      P[n] *= dA;
    }
  }
  size_t outb = ((size_t)(b * GCH + g) * 16) * 512 + d;
#pragma unroll
  for (int n = 0; n < 16; ++n) { Sbuf[outb + (size_t)n * 512] = h[n]; Pbuf[outb + (size_t)n * 512] = P[n]; }
}

// ---------------- kernel 5: parallel chunk combine (2-level segmented scan) ----------------
// chains = (b,n,d): 16384. 8 lanes per chain (seg of 16 chunks each), shfl affine scan.
__global__ __launch_bounds__(256) void k_comb(const float* __restrict__ Pbuf,
                                              const float* __restrict__ Sbuf,
                                              float* __restrict__ Hinit){
  int bid = blockIdx.x;            // [0,512)
  int b  = bid >> 8;
  int n  = (bid >> 4) & 15;
  int d0 = (bid & 15) * 32;
  int t = threadIdx.x;
  int w = t >> 6, li = t & 63;
  int j = li >> 3;                 // segment index [0,8)
  int d = d0 + w * 8 + (li & 7);
  const size_t gstride = (size_t)16 * 512;
  size_t base = ((size_t)(b * GCH) * 16 + n) * 512 + d;
  float P = 1.f, S = 0.f;
#pragma unroll 4
  for (int i = 0; i < 16; ++i) {
    size_t id = base + (size_t)(16 * j + i) * gstride;
    float p = Pbuf[id], s = Sbuf[id];
    S = p * S + s;
    P = p * P;
  }
  // inclusive affine scan over j (stride 8 within wave)
#pragma unroll
  for (int k = 1; k < 8; k <<= 1) {
    float Pp = __shfl_up(P, k * 8);
    float Sp = __shfl_up(S, k * 8);
    if (j >= k) { S = P * Sp + S; P = P * Pp; }
  }
  float hseg = __shfl_up(S, 8);    // exclusive: state before segment j
  if (j == 0) hseg = 0.f;
  float h = hseg;
#pragma unroll 4
  for (int i = 0; i < 16; ++i) {
    size_t id = base + (size_t)(16 * j + i) * gstride;
    float p = Pbuf[id], s = Sbuf[id];
    Hinit[id] = h;
    h = p * h + s;
  }
}

// ---------------- kernel 6: scan pass 2 + y + D-skip + gate -> yg bf16 ----------------
__global__ __launch_bounds__(256) void k_scan2(const ushort* __restrict__ deltab,
                                               const ushort* __restrict__ xcb,
                                               const float* __restrict__ BCbuf,
                                               const float* __restrict__ anv,
                                               const float* __restrict__ Hinit,
                                               const ushort* __restrict__ gb,
                                               const float* __restrict__ Dw,
                                               ushort* __restrict__ ygb){
  __shared__ float bcs[LCH][32];
  int bid = blockIdx.x;
  int b = bid >> 8;
  int g = (bid >> 1) & 127;
  int dh = bid & 1;
  int d = dh * 256 + threadIdx.x;
  int base = b * SEQ + g * LCH;
  {
    float2 v = *reinterpret_cast<const float2*>(&BCbuf[(size_t)base * 32 + threadIdx.x * 2]);
    *reinterpret_cast<float2*>(&((float*)bcs)[threadIdx.x * 2]) = v;
  }
  __syncthreads();
  float an[16], h[16];
  size_t hb0 = ((size_t)(b * GCH + g) * 16) * 512 + d;
#pragma unroll
  for (int n = 0; n < 16; ++n) { an[n] = anv[n * 512 + d]; h[n] = Hinit[hb0 + (size_t)n * 512]; }
  float Dd = Dw[d];
  for (int s = 0; s < LCH; ++s) {
    int row = base + s;
    float dl = bf2f(deltab[(size_t)row * 512 + d]);
    float xv = bf2f(xcb[(size_t)row * 512 + d]);
    float dx = dl * xv;
    float y = 0.f;
#pragma unroll
    for (int n = 0; n < 16; ++n) {
      float dA = __expf(dl * an[n]);
      h[n] = dA * h[n] + dx * bcs[s][n];
      y += h[n] * bcs[s][16 + n];
    }
    float zg = bf2f(gb[(size_t)row * 512 + d]);
    ygb[(size_t)row * 512 + d] = f2bf((y + xv * Dd) * zg);
  }
}

// ---------------- kernel 7: GEMM3 (bf16 MFMA) out = residual + yg.Wout^T ----------------
__global__ __launch_bounds__(256) void k_gemm3(const ushort* __restrict__ A,   // yg [4096][512]
                                               const ushort* __restrict__ B,   // wout [256][512]
                                               const float* __restrict__ x,
                                               float* __restrict__ out){
  __shared__ ushort Als[128][72];
  __shared__ ushort Bls[64][72];
  int m0 = blockIdx.x * 128, n0 = blockIdx.y * 64;
  int t = threadIdx.x;
  int w = t >> 6, l = t & 63;
  int wr = w >> 1, wc = w & 1;
  f32x4 acc[4][2] = {};
  int sr = t >> 3, sc = t & 7;
  for (int k0 = 0; k0 < DINNER; k0 += 64) {
#pragma unroll
    for (int p = 0; p < 4; ++p) {
      int r = sr + p * 32;
      *reinterpret_cast<int4*>(&Als[r][sc * 8]) =
        *reinterpret_cast<const int4*>(&A[((size_t)(m0 + r)) * DINNER + k0 + sc * 8]);
    }
#pragma unroll
    for (int p = 0; p < 2; ++p) {
      int r = sr + p * 32;
      *reinterpret_cast<int4*>(&Bls[r][sc * 8]) =
        *reinterpret_cast<const int4*>(&B[((size_t)(n0 + r)) * DINNER + k0 + sc * 8]);
    }
    __syncthreads();
#pragma unroll
    for (int ks = 0; ks < 2; ++ks) {
      s16x8 af[4], bf[2];
      int kk = ks * 32 + 8 * (l >> 4);
#pragma unroll
      for (int i = 0; i < 4; ++i)
        af[i] = *reinterpret_cast<const s16x8*>(&Als[wr * 64 + i * 16 + (l & 15)][kk]);
#pragma unroll
      for (int i = 0; i < 2; ++i)
        bf[i] = *reinterpret_cast<const s16x8*>(&Bls[wc * 32 + i * 16 + (l & 15)][kk]);
#pragma unroll
      for (int mi = 0; mi < 4; ++mi)
#pragma unroll
        for (int ni = 0; ni < 2; ++ni)
          acc[mi][ni] = __builtin_amdgcn_mfma_f32_16x16x32_bf16(af[mi], bf[ni], acc[mi][ni], 0, 0, 0);
    }
    __syncthreads();
  }
  int rq = l >> 4, cc = l & 15;
#pragma unroll
  for (int mi = 0; mi < 4; ++mi)
#pragma unroll
    for (int ni = 0; ni < 2; ++ni) {
      int n = n0 + wc * 32 + ni * 16 + cc;
      int mB = m0 + wr * 64 + mi * 16 + rq * 4;
#pragma unroll
      for (int r2 = 0; r2 < 4; ++r2) {
        int m = mB + r2;
        int b = m >> 11;
        int lb = m & (SEQ - 1);
        size_t addr = ((size_t)(b * DMODEL + n)) * SEQ + lb;
        out[addr] = acc[mi][ni][r2] + x[addr];
      }
    }
}

extern "C" void kernel_launch(void* const* d_in, const int* in_sizes, int n_in,
                              void* d_out, int out_size, void* d_ws, size_t ws_size,
                              hipStream_t stream) {
  const float* x          = (const float*)d_in[0];
  const float* norm_w     = (const float*)d_in[1];
  const float* in_proj_w  = (const float*)d_in[2];
  const float* conv_w     = (const float*)d_in[3];
  const float* conv_b     = (const float*)d_in[4];
  const float* x_proj_w   = (const float*)d_in[5];
  const float* dt_proj_w  = (const float*)d_in[6];
  const float* dt_proj_b  = (const float*)d_in[7];
  const float* A_log      = (const float*)d_in[8];
  const float* Dw         = (const float*)d_in[9];
  const float* out_proj_w = (const float*)d_in[10];
  float* out = (float*)d_out;

  float* ws    = (float*)d_ws;
  float* BCbuf = ws;                                   // 4096*32      = 131072 f
  float* Pbuf  = BCbuf + (size_t)4096 * 32;            // 2*128*16*512 = 2097152 f
  float* Sbuf  = Pbuf  + (size_t)2 * GCH * 16 * 512;
  float* Hinit = Sbuf  + (size_t)2 * GCH * 16 * 512;
  float* anv   = Hinit + (size_t)2 * GCH * 16 * 512;   // 16*512
  ushort* hb   = (ushort*)(anv + 16 * 512);            // 4096*256
  ushort* wib  = hb   + (size_t)4096 * 256;            // 1024*256
  ushort* wob  = wib  + (size_t)1024 * 256;            // 256*512
  ushort* xzb  = wob  + (size_t)256 * 512;             // 4096*1024
  ushort* xcb  = xzb  + (size_t)4096 * 1024;           // 4096*512
  ushort* gbuf = xcb  + (size_t)4096 * 512;            // 4096*512
  ushort* delt = gbuf + (size_t)4096 * 512;            // 4096*512
  ushort* ygb  = delt + (size_t)4096 * 512;            // 4096*512

  k_prep <<<450,          256, 0, stream>>>(x, norm_w, in_proj_w, out_proj_w, A_log, hb, wib, wob, anv);
  k_gemm1<<<dim3(32, 8),  256, 0, stream>>>(hb, wib, xzb);
  k_cxp  <<<1024,         256, 0, stream>>>(xzb, conv_w, conv_b, x_proj_w, dt_proj_w, dt_proj_b, xcb, gbuf, BCbuf, delt);
  k_scan1<<<512,          256, 0, stream>>>(delt, xcb, BCbuf, anv, Pbuf, Sbuf);
  k_comb <<<512,          256, 0, stream>>>(Pbuf, Sbuf, Hinit);
  k_scan2<<<512,          256, 0, stream>>>(delt, xcb, BCbuf, anv, Hinit, gbuf, Dw, ygb);
  k_gemm3<<<dim3(32, 4),  256, 0, stream>>>(ygb, wob, x, out);
}